// Round 8
// baseline (252.792 us; speedup 1.0000x reference)
//
#include <hip/hip_runtime.h>
#include <math.h>

#define NB 2
#define NC 128
#define NN 4096
#define C2L 2.88539008177792681472f   // 2*log2(e)

typedef __attribute__((ext_vector_type(8))) short short8;
typedef __attribute__((ext_vector_type(4))) float f32x4;

// bf16 inputs, transposed to [n][k] (k-contiguous for MFMA fragments).
__device__ unsigned short g_Tb[NB][NN][NC];
__device__ unsigned short g_Sb[NB][NN][NC];
__device__ float g_tsqr[NB][NN];
__device__ float g_ssqr[NB][NN];
__device__ float g_rowS[NB][NN];    // -(2*log2e/(rowmin+eps))
__device__ float g_rowLZ[NB][NN];   // log2(ZB)
__device__ float g_rowE[NB][NN];    // mA
__device__ float g_colS[NB][NN];
__device__ float g_colLZ[NB][NN];
__device__ float g_colE[NB][NN];
__device__ float g_colpart[NB][256][NN];  // per-stripe col partials (8MB)
__device__ float g_rowpart[NB][4][NN];    // per-jquarter row partials

#if __has_builtin(__builtin_amdgcn_exp2f)
__device__ __forceinline__ float fexp2(float x) { return __builtin_amdgcn_exp2f(x); }
#else
__device__ __forceinline__ float fexp2(float x) { return exp2f(x); }
#endif

__device__ __forceinline__ unsigned f2bf(float f) {
    unsigned u = __float_as_uint(f);
    u += 0x7FFFu + ((u >> 16) & 1u);   // RNE
    return u >> 16;
}

// fp32 [k][n] -> bf16 [n][k], fused with squared-norm computation.
__global__ void __launch_bounds__(256) transpose_prep(const float* __restrict__ src,
                                                      const float* __restrict__ tgt) {
    __shared__ float ls[NC][68];
    int bid = blockIdx.x;              // 2 mat x 2 b x 64 n-chunks = 256
    int mat = bid >> 7;
    int b   = (bid >> 6) & 1;
    int n0  = (bid & 63) << 6;
    int tid = threadIdx.x;
    const float* in = (mat ? tgt : src) + (size_t)b * NC * NN;
    unsigned short (*out)[NC] = mat ? g_Tb[b] : g_Sb[b];
    float* sq = mat ? g_tsqr[b] : g_ssqr[b];

    for (int idx = tid; idx < NC * 16; idx += 256) {
        int k = idx >> 4, c4 = (idx & 15) << 2;
        *(float4*)&ls[k][c4] = *(const float4*)(in + (size_t)k * NN + n0 + c4);
    }
    __syncthreads();
    {
        int n = tid & 63, c = tid >> 6;
        for (int cc = c; cc < 16; cc += 4) {
            unsigned uo[4];
            #pragma unroll
            for (int e = 0; e < 4; ++e) {
                unsigned lo = f2bf(ls[cc * 8 + 2 * e][n]);
                unsigned hi = f2bf(ls[cc * 8 + 2 * e + 1][n]);
                uo[e] = lo | (hi << 16);
            }
            *(uint4*)&out[n0 + n][cc * 8] = make_uint4(uo[0], uo[1], uo[2], uo[3]);
        }
    }
    if (tid < 64) {
        float s = 0.f;
        #pragma unroll 8
        for (int k = 0; k < NC; ++k) { float v = ls[k][tid]; s = fmaf(v, v, s); }
        sq[n0 + tid] = s;
    }
}

// Barrier-free sweep, depth-2 register prefetch. Block owns 16 T-rows x
// 1024 S-cols (16 j-tiles). Two statically-named B-buffers (b0/b1); loads
// for tile jt+2 are issued right after tile jt's MFMAs consume b0 -> the
// load->use distance spans a full iteration (~800+cy), covering L2/L3
// latency without barriers. ~90 VGPR -> 5 waves/SIMD.
template<int PASS>
__global__ void __launch_bounds__(256, 2) sweep_kernel() {
    __shared__ float redrow[4][16];

    int bid    = blockIdx.x;           // NB*256*4 = 2048
    int b      = (bid >> 2) & 1;
    int qtr    = bid & 3;
    int stripe = bid >> 3;
    int i0     = stripe * 16;
    int jbase  = qtr * 1024;
    int tid = threadIdx.x;
    int w = tid >> 6, lane = tid & 63, q = lane >> 4, x = lane & 15;

    // hoisted A-fragments: rows i0 + x, k-chunk kk*4+q
    short8 af[4];
    #pragma unroll
    for (int kk = 0; kk < 4; ++kk)
        af[kk] = *(const short8*)&g_Tb[b][i0 + x][(kk * 4 + q) * 8];

    // hoisted per-row data (rows i0 + q*4 + v)
    float tq[4], rS[4], rC[4];
    #pragma unroll
    for (int v = 0; v < 4; ++v) {
        int row = i0 + q * 4 + v;
        tq[v] = g_tsqr[b][row];
        rS[v] = (PASS >= 2) ? g_rowS[b][row] : 0.f;
        rC[v] = (PASS == 3) ? (C2L - g_rowLZ[b][row]) : 0.f;
    }

    float rstate[4];
    #pragma unroll
    for (int v = 0; v < 4; ++v)
        rstate[v] = (PASS == 1) ? 3.0e38f : (PASS == 2 ? 0.f : -3.0e38f);

    int colb = w * 16 + x;             // this wave's col within a 64-col tile

    // prologue: prefetch tiles 0 (b0) and 1 (b1)
    short8 b0[4], b1[4];
    float sq0, cS0 = 0.f, cC0 = 0.f, sq1, cS1 = 0.f, cC1 = 0.f;
    {
        const unsigned short* r0 = &g_Sb[b][jbase + colb][0];
        const unsigned short* r1 = &g_Sb[b][jbase + 64 + colb][0];
        #pragma unroll
        for (int kk = 0; kk < 4; ++kk) {
            b0[kk] = *(const short8*)(r0 + (kk * 4 + q) * 8);
            b1[kk] = *(const short8*)(r1 + (kk * 4 + q) * 8);
        }
        sq0 = g_ssqr[b][jbase + colb];
        sq1 = g_ssqr[b][jbase + 64 + colb];
        if (PASS >= 2) { cS0 = g_colS[b][jbase + colb]; cS1 = g_colS[b][jbase + 64 + colb]; }
        if (PASS == 3) { cC0 = C2L - g_colLZ[b][jbase + colb]; cC1 = C2L - g_colLZ[b][jbase + 64 + colb]; }
    }

    for (int jt = 0; jt < 16; jt += 2) {
        // ---- even tile: consume b0, reissue b0 for jt+2 ----
        {
            f32x4 acc = {0.f, 0.f, 0.f, 0.f};
            #pragma unroll
            for (int kk = 0; kk < 4; ++kk)
                acc = __builtin_amdgcn_mfma_f32_16x16x32_bf16(af[kk], b0[kk], acc, 0, 0, 0);
            float sq_c = sq0, cS_c = cS0, cC_c = cC0;
            if (jt + 2 < 16) {
                int coln = jbase + (jt + 2) * 64 + colb;
                const unsigned short* nr = &g_Sb[b][coln][0];
                #pragma unroll
                for (int kk = 0; kk < 4; ++kk) b0[kk] = *(const short8*)(nr + (kk * 4 + q) * 8);
                sq0 = g_ssqr[b][coln];
                if (PASS >= 2) cS0 = g_colS[b][coln];
                if (PASS == 3) cC0 = C2L - g_colLZ[b][coln];
            }
            float colval;
            if (PASS == 1) {
                colval = 3.0e38f;
                #pragma unroll
                for (int v = 0; v < 4; ++v) {
                    float dv = fmaxf(fmaf(-2.f, acc[v], tq[v] + sq_c), 0.f);
                    rstate[v] = fminf(rstate[v], dv);
                    colval = fminf(colval, dv);
                }
                colval = fminf(colval, __shfl_xor(colval, 16));
                colval = fminf(colval, __shfl_xor(colval, 32));
            } else if (PASS == 2) {
                colval = 0.f;
                #pragma unroll
                for (int v = 0; v < 4; ++v) {
                    float dv = fmaxf(fmaf(-2.f, acc[v], tq[v] + sq_c), 0.f);
                    colval    += fexp2(fmaf(dv, cS_c, C2L));
                    rstate[v] += fexp2(fmaf(dv, rS[v], C2L));
                }
                colval += __shfl_xor(colval, 16);
                colval += __shfl_xor(colval, 32);
            } else {
                colval = -3.0e38f;
                #pragma unroll
                for (int v = 0; v < 4; ++v) {
                    float dv = fmaxf(fmaf(-2.f, acc[v], tq[v] + sq_c), 0.f);
                    rstate[v] = fmaxf(rstate[v], fmaf(dv, cS_c, cC_c));
                    colval    = fmaxf(colval, fmaf(dv, rS[v], rC[v]));
                }
                colval = fmaxf(colval, __shfl_xor(colval, 16));
                colval = fmaxf(colval, __shfl_xor(colval, 32));
            }
            if (q == 0)
                g_colpart[b][stripe][jbase + jt * 64 + colb] = colval;
        }
        // ---- odd tile: consume b1, reissue b1 for jt+3 ----
        {
            f32x4 acc = {0.f, 0.f, 0.f, 0.f};
            #pragma unroll
            for (int kk = 0; kk < 4; ++kk)
                acc = __builtin_amdgcn_mfma_f32_16x16x32_bf16(af[kk], b1[kk], acc, 0, 0, 0);
            float sq_c = sq1, cS_c = cS1, cC_c = cC1;
            if (jt + 3 < 16) {
                int coln = jbase + (jt + 3) * 64 + colb;
                const unsigned short* nr = &g_Sb[b][coln][0];
                #pragma unroll
                for (int kk = 0; kk < 4; ++kk) b1[kk] = *(const short8*)(nr + (kk * 4 + q) * 8);
                sq1 = g_ssqr[b][coln];
                if (PASS >= 2) cS1 = g_colS[b][coln];
                if (PASS == 3) cC1 = C2L - g_colLZ[b][coln];
            }
            float colval;
            if (PASS == 1) {
                colval = 3.0e38f;
                #pragma unroll
                for (int v = 0; v < 4; ++v) {
                    float dv = fmaxf(fmaf(-2.f, acc[v], tq[v] + sq_c), 0.f);
                    rstate[v] = fminf(rstate[v], dv);
                    colval = fminf(colval, dv);
                }
                colval = fminf(colval, __shfl_xor(colval, 16));
                colval = fminf(colval, __shfl_xor(colval, 32));
            } else if (PASS == 2) {
                colval = 0.f;
                #pragma unroll
                for (int v = 0; v < 4; ++v) {
                    float dv = fmaxf(fmaf(-2.f, acc[v], tq[v] + sq_c), 0.f);
                    colval    += fexp2(fmaf(dv, cS_c, C2L));
                    rstate[v] += fexp2(fmaf(dv, rS[v], C2L));
                }
                colval += __shfl_xor(colval, 16);
                colval += __shfl_xor(colval, 32);
            } else {
                colval = -3.0e38f;
                #pragma unroll
                for (int v = 0; v < 4; ++v) {
                    float dv = fmaxf(fmaf(-2.f, acc[v], tq[v] + sq_c), 0.f);
                    rstate[v] = fmaxf(rstate[v], fmaf(dv, cS_c, cC_c));
                    colval    = fmaxf(colval, fmaf(dv, rS[v], rC[v]));
                }
                colval = fmaxf(colval, __shfl_xor(colval, 16));
                colval = fmaxf(colval, __shfl_xor(colval, 32));
            }
            if (q == 0)
                g_colpart[b][stripe][jbase + (jt + 1) * 64 + colb] = colval;
        }
    }

    // row reduction: over x-lanes (16), then over waves via LDS
    #pragma unroll
    for (int off = 1; off < 16; off <<= 1)
        #pragma unroll
        for (int v = 0; v < 4; ++v) {
            float o = __shfl_xor(rstate[v], off);
            rstate[v] = (PASS == 1) ? fminf(rstate[v], o)
                       : (PASS == 2) ? rstate[v] + o : fmaxf(rstate[v], o);
        }
    if (x == 0)
        #pragma unroll
        for (int v = 0; v < 4; ++v)
            redrow[w][q * 4 + v] = rstate[v];
    __syncthreads();
    if (tid < 16) {
        float a = redrow[0][tid], c = redrow[1][tid], d = redrow[2][tid], e = redrow[3][tid];
        float v = (PASS == 1) ? fminf(fminf(a, c), fminf(d, e))
                 : (PASS == 2) ? (a + c) + (d + e)
                 : fmaxf(fmaxf(a, c), fmaxf(d, e));
        g_rowpart[b][qtr][i0 + tid] = v;
    }
}

// Wide reduce: 128 blocks; 4 lanes per column, each covering 64 stripes.
template<int PASS>
__global__ void __launch_bounds__(256) reduce_kernel() {
    int bid = blockIdx.x;             // NB*64 = 128
    int b = bid >> 6, g = bid & 63;
    int tid = threadIdx.x;
    int col = g * 64 + (tid >> 2);
    int part = tid & 3;
    float acc = (PASS == 1) ? 3.0e38f : (PASS == 2 ? 0.f : -3.0e38f);
    #pragma unroll 8
    for (int s = part * 64; s < part * 64 + 64; ++s) {
        float v = g_colpart[b][s][col];
        acc = (PASS == 1) ? fminf(acc, v) : (PASS == 2) ? acc + v : fmaxf(acc, v);
    }
    #pragma unroll
    for (int off = 1; off < 4; off <<= 1) {
        float o = __shfl_xor(acc, off);
        acc = (PASS == 1) ? fminf(acc, o) : (PASS == 2) ? acc + o : fmaxf(acc, o);
    }
    if (part == 0) {
        if (PASS == 1) g_colS[b][col]  = -(C2L / (acc + 1e-5f));
        if (PASS == 2) g_colLZ[b][col] = log2f(acc);
        if (PASS == 3) g_colE[b][col]  = fexp2(acc);
    }
    if (tid < 64) {
        int r = g * 64 + tid;
        float p0 = g_rowpart[b][0][r], p1 = g_rowpart[b][1][r];
        float p2 = g_rowpart[b][2][r], p3 = g_rowpart[b][3][r];
        float rv = (PASS == 1) ? fminf(fminf(p0, p1), fminf(p2, p3))
                 : (PASS == 2) ? (p0 + p1) + (p2 + p3)
                 : fmaxf(fmaxf(p0, p1), fmaxf(p2, p3));
        if (PASS == 1) g_rowS[b][r]  = -(C2L / (rv + 1e-5f));
        if (PASS == 2) g_rowLZ[b][r] = log2f(rv);
        if (PASS == 3) g_rowE[b][r]  = fexp2(rv);
    }
}

__global__ void final_kernel(float* __restrict__ out) {
    int tid = threadIdx.x;
    float s[4] = {0.f, 0.f, 0.f, 0.f};
    for (int i = tid; i < NN; i += 256) {
        s[0] += g_rowE[0][i];
        s[1] += g_rowE[1][i];
        s[2] += g_colE[0][i];
        s[3] += g_colE[1][i];
    }
    __shared__ float red[4][4];
    int lane = tid & 63, w = tid >> 6;
    #pragma unroll
    for (int t = 0; t < 4; ++t) {
        float v = s[t];
        #pragma unroll
        for (int off = 32; off; off >>= 1) v += __shfl_down(v, off);
        if (lane == 0) red[t][w] = v;
    }
    __syncthreads();
    if (tid == 0) {
        float o = 0.f;
        #pragma unroll
        for (int t = 0; t < 4; ++t) {
            float S = red[t][0] + red[t][1] + red[t][2] + red[t][3];
            o += logf(S);
        }
        out[0] = logf((float)NN) - 0.25f * o;
    }
}

extern "C" void kernel_launch(void* const* d_in, const int* in_sizes, int n_in,
                              void* d_out, int out_size, void* d_ws, size_t ws_size,
                              hipStream_t stream) {
    const float* src = (const float*)d_in[0];
    const float* tgt = (const float*)d_in[1];
    (void)in_sizes; (void)n_in; (void)d_ws; (void)ws_size; (void)out_size;

    transpose_prep<<<256, 256, 0, stream>>>(src, tgt);
    sweep_kernel<1><<<2048, 256, 0, stream>>>();
    reduce_kernel<1><<<128, 256, 0, stream>>>();
    sweep_kernel<2><<<2048, 256, 0, stream>>>();
    reduce_kernel<2><<<128, 256, 0, stream>>>();
    sweep_kernel<3><<<2048, 256, 0, stream>>>();
    reduce_kernel<3><<<128, 256, 0, stream>>>();
    final_kernel<<<1, 256, 0, stream>>>((float*)d_out);
}

// Round 9
// 143.847 us; speedup vs baseline: 1.7574x; 1.7574x over previous
//
#include <hip/hip_runtime.h>
#include <math.h>

#define NB 2
#define NC 128
#define NN 4096
#define C2L 2.88539008177792681472f   // 2*log2(e)

typedef __attribute__((ext_vector_type(8))) short short8;
typedef __attribute__((ext_vector_type(4))) float f32x4;

// bf16 inputs, transposed to [n][k] (k-contiguous for MFMA fragments).
__device__ unsigned short g_Tb[NB][NN][NC];
__device__ unsigned short g_Sb[NB][NN][NC];
__device__ float g_tsqr[NB][NN];
__device__ float g_ssqr[NB][NN];
__device__ float g_rowS[NB][NN];    // -(2*log2e/(rowmin+eps))
__device__ float g_rowLZ[NB][NN];   // log2(ZB)
__device__ float g_rowE[NB][NN];    // mA
__device__ float g_colS[NB][NN];
__device__ float g_colLZ[NB][NN];
__device__ float g_colE[NB][NN];
__device__ float g_colpart[NB][64][NN];  // [ti*2+ih] partials, exclusive
__device__ float g_rowpart[NB][64][NN];  // [tj*2+jh] partials, exclusive

#if __has_builtin(__builtin_amdgcn_exp2f)
__device__ __forceinline__ float fexp2(float x) { return __builtin_amdgcn_exp2f(x); }
#else
__device__ __forceinline__ float fexp2(float x) { return exp2f(x); }
#endif

__device__ __forceinline__ unsigned f2bf(float f) {
    unsigned u = __float_as_uint(f);
    u += 0x7FFFu + ((u >> 16) & 1u);   // RNE
    return u >> 16;
}

// fp32 [k][n] -> bf16 [n][k], fused with squared-norm computation.
__global__ void __launch_bounds__(256) transpose_prep(const float* __restrict__ src,
                                                      const float* __restrict__ tgt) {
    __shared__ float ls[NC][68];
    int bid = blockIdx.x;              // 2 mat x 2 b x 64 n-chunks = 256
    int mat = bid >> 7;
    int b   = (bid >> 6) & 1;
    int n0  = (bid & 63) << 6;
    int tid = threadIdx.x;
    const float* in = (mat ? tgt : src) + (size_t)b * NC * NN;
    unsigned short (*out)[NC] = mat ? g_Tb[b] : g_Sb[b];
    float* sq = mat ? g_tsqr[b] : g_ssqr[b];

    for (int idx = tid; idx < NC * 16; idx += 256) {
        int k = idx >> 4, c4 = (idx & 15) << 2;
        *(float4*)&ls[k][c4] = *(const float4*)(in + (size_t)k * NN + n0 + c4);
    }
    __syncthreads();
    {
        int n = tid & 63, c = tid >> 6;
        for (int cc = c; cc < 16; cc += 4) {
            unsigned uo[4];
            #pragma unroll
            for (int e = 0; e < 4; ++e) {
                unsigned lo = f2bf(ls[cc * 8 + 2 * e][n]);
                unsigned hi = f2bf(ls[cc * 8 + 2 * e + 1][n]);
                uo[e] = lo | (hi << 16);
            }
            *(uint4*)&out[n0 + n][cc * 8] = make_uint4(uo[0], uo[1], uo[2], uo[3]);
        }
    }
    if (tid < 64) {
        float s = 0.f;
        #pragma unroll 8
        for (int k = 0; k < NC; ++k) { float v = ls[k][tid]; s = fmaf(v, v, s); }
        sq[n0 + tid] = s;
    }
}

// 128x128-tile sweep (round-2 GEMM economics: 4 B/output fragment traffic,
// the minimum-bytes config against the measured ~6 TB/s cache-tier wall).
// 4 waves, each owning a 64x64 quadrant; reductions kept in registers and
// stored to exclusive partial slots (no atomics, no barriers in main path).
template<int PASS>
__global__ void __launch_bounds__(256) sweep_kernel() {
    int bid = blockIdx.x;              // NB*32*32 = 2048
    int b  = bid >> 10;
    int t  = bid & 1023;
    int ti = t >> 5, tj = t & 31;
    int wave = threadIdx.x >> 6, lane = threadIdx.x & 63;
    int q = lane >> 4, x = lane & 15;
    int ih = wave >> 1, jh = wave & 1;
    int iw = ti * 128 + ih * 64;
    int jw = tj * 128 + jh * 64;

    f32x4 acc[4][4];
    #pragma unroll
    for (int m = 0; m < 4; ++m)
        #pragma unroll
        for (int n = 0; n < 4; ++n)
            acc[m][n] = (f32x4){0.f, 0.f, 0.f, 0.f};

    #pragma unroll
    for (int kk = 0; kk < 4; ++kk) {
        int ko = (kk * 4 + q) * 8;
        short8 af[4], bfr[4];
        #pragma unroll
        for (int m = 0; m < 4; ++m)
            af[m] = *(const short8*)&g_Tb[b][iw + m * 16 + x][ko];
        #pragma unroll
        for (int n = 0; n < 4; ++n)
            bfr[n] = *(const short8*)&g_Sb[b][jw + n * 16 + x][ko];
        #pragma unroll
        for (int m = 0; m < 4; ++m)
            #pragma unroll
            for (int n = 0; n < 4; ++n)
                acc[m][n] = __builtin_amdgcn_mfma_f32_16x16x32_bf16(af[m], bfr[n], acc[m][n], 0, 0, 0);
    }

    // d(row,col): row = iw + m*16 + q*4 + v, col = jw + n*16 + x
    float tq[16], sq4[4];
    #pragma unroll
    for (int m = 0; m < 4; ++m)
        #pragma unroll
        for (int v = 0; v < 4; ++v)
            tq[m * 4 + v] = g_tsqr[b][iw + m * 16 + q * 4 + v];
    #pragma unroll
    for (int n = 0; n < 4; ++n) sq4[n] = g_ssqr[b][jw + n * 16 + x];

    float rstate[16], cstate[4];
    float rS[16], rC[16], cS[4], cC[4];
    if (PASS >= 2) {
        #pragma unroll
        for (int e = 0; e < 16; ++e) {
            int row = iw + (e >> 2) * 16 + q * 4 + (e & 3);
            rS[e] = g_rowS[b][row];
            if (PASS == 3) rC[e] = C2L - g_rowLZ[b][row];
        }
        #pragma unroll
        for (int n = 0; n < 4; ++n) {
            int col = jw + n * 16 + x;
            cS[n] = g_colS[b][col];
            if (PASS == 3) cC[n] = C2L - g_colLZ[b][col];
        }
    }
    #pragma unroll
    for (int e = 0; e < 16; ++e)
        rstate[e] = (PASS == 1) ? 3.0e38f : (PASS == 2 ? 0.f : -3.0e38f);
    #pragma unroll
    for (int n = 0; n < 4; ++n)
        cstate[n] = (PASS == 1) ? 3.0e38f : (PASS == 2 ? 0.f : -3.0e38f);

    #pragma unroll
    for (int m = 0; m < 4; ++m)
        #pragma unroll
        for (int n = 0; n < 4; ++n)
            #pragma unroll
            for (int v = 0; v < 4; ++v) {
                float dv = fmaxf(fmaf(-2.f, acc[m][n][v], tq[m * 4 + v] + sq4[n]), 0.f);
                if (PASS == 1) {
                    rstate[m * 4 + v] = fminf(rstate[m * 4 + v], dv);
                    cstate[n]         = fminf(cstate[n], dv);
                } else if (PASS == 2) {
                    rstate[m * 4 + v] += fexp2(fmaf(dv, rS[m * 4 + v], C2L));
                    cstate[n]         += fexp2(fmaf(dv, cS[n], C2L));
                } else {
                    // A-direction (row max) uses col params; B-direction uses row params
                    rstate[m * 4 + v] = fmaxf(rstate[m * 4 + v], fmaf(dv, cS[n], cC[n]));
                    cstate[n]         = fmaxf(cstate[n], fmaf(dv, rS[m * 4 + v], rC[m * 4 + v]));
                }
            }

    // row reduction over 16 x-lanes -> exclusive partial store
    #pragma unroll
    for (int off = 1; off < 16; off <<= 1)
        #pragma unroll
        for (int e = 0; e < 16; ++e) {
            float o = __shfl_xor(rstate[e], off);
            rstate[e] = (PASS == 1) ? fminf(rstate[e], o)
                       : (PASS == 2) ? rstate[e] + o : fmaxf(rstate[e], o);
        }
    if (x == 0)
        #pragma unroll
        for (int e = 0; e < 16; ++e)
            g_rowpart[b][tj * 2 + jh][iw + (e >> 2) * 16 + q * 4 + (e & 3)] = rstate[e];

    // col reduction over 4 q-groups -> exclusive partial store
    #pragma unroll
    for (int off = 16; off < 64; off <<= 1)
        #pragma unroll
        for (int n = 0; n < 4; ++n) {
            float o = __shfl_xor(cstate[n], off);
            cstate[n] = (PASS == 1) ? fminf(cstate[n], o)
                       : (PASS == 2) ? cstate[n] + o : fmaxf(cstate[n], o);
        }
    if (q == 0)
        #pragma unroll
        for (int n = 0; n < 4; ++n)
            g_colpart[b][ti * 2 + ih][jw + n * 16 + x] = cstate[n];
}

// Reduce 64 exclusive partials per row/col; 4 lanes per element, 16 slots each.
template<int PASS>
__global__ void __launch_bounds__(256) reduce_kernel() {
    int bid = blockIdx.x;             // NB*64 = 128
    int b = bid >> 6, g = bid & 63;
    int tid = threadIdx.x;
    int el = g * 64 + (tid >> 2);
    int part = tid & 3;

    float ca = (PASS == 1) ? 3.0e38f : (PASS == 2 ? 0.f : -3.0e38f);
    float ra = ca;
    #pragma unroll 4
    for (int s = part * 16; s < part * 16 + 16; ++s) {
        float cv = g_colpart[b][s][el];
        float rv = g_rowpart[b][s][el];
        if (PASS == 1) { ca = fminf(ca, cv); ra = fminf(ra, rv); }
        else if (PASS == 2) { ca += cv; ra += rv; }
        else { ca = fmaxf(ca, cv); ra = fmaxf(ra, rv); }
    }
    #pragma unroll
    for (int off = 1; off < 4; off <<= 1) {
        float co = __shfl_xor(ca, off), ro = __shfl_xor(ra, off);
        if (PASS == 1) { ca = fminf(ca, co); ra = fminf(ra, ro); }
        else if (PASS == 2) { ca += co; ra += ro; }
        else { ca = fmaxf(ca, co); ra = fmaxf(ra, ro); }
    }
    if (part == 0) {
        if (PASS == 1) { g_colS[b][el] = -(C2L / (ca + 1e-5f)); g_rowS[b][el] = -(C2L / (ra + 1e-5f)); }
        if (PASS == 2) { g_colLZ[b][el] = log2f(ca);            g_rowLZ[b][el] = log2f(ra); }
        if (PASS == 3) { g_colE[b][el] = fexp2(ca);             g_rowE[b][el] = fexp2(ra); }
    }
}

__global__ void final_kernel(float* __restrict__ out) {
    int tid = threadIdx.x;
    float s[4] = {0.f, 0.f, 0.f, 0.f};
    for (int i = tid; i < NN; i += 256) {
        s[0] += g_rowE[0][i];
        s[1] += g_rowE[1][i];
        s[2] += g_colE[0][i];
        s[3] += g_colE[1][i];
    }
    __shared__ float red[4][4];
    int lane = tid & 63, w = tid >> 6;
    #pragma unroll
    for (int t = 0; t < 4; ++t) {
        float v = s[t];
        #pragma unroll
        for (int off = 32; off; off >>= 1) v += __shfl_down(v, off);
        if (lane == 0) red[t][w] = v;
    }
    __syncthreads();
    if (tid == 0) {
        float o = 0.f;
        #pragma unroll
        for (int t = 0; t < 4; ++t) {
            float S = red[t][0] + red[t][1] + red[t][2] + red[t][3];
            o += logf(S);
        }
        out[0] = logf((float)NN) - 0.25f * o;
    }
}

extern "C" void kernel_launch(void* const* d_in, const int* in_sizes, int n_in,
                              void* d_out, int out_size, void* d_ws, size_t ws_size,
                              hipStream_t stream) {
    const float* src = (const float*)d_in[0];
    const float* tgt = (const float*)d_in[1];
    (void)in_sizes; (void)n_in; (void)d_ws; (void)ws_size; (void)out_size;

    transpose_prep<<<256, 256, 0, stream>>>(src, tgt);
    sweep_kernel<1><<<2048, 256, 0, stream>>>();
    reduce_kernel<1><<<128, 256, 0, stream>>>();
    sweep_kernel<2><<<2048, 256, 0, stream>>>();
    reduce_kernel<2><<<128, 256, 0, stream>>>();
    sweep_kernel<3><<<2048, 256, 0, stream>>>();
    reduce_kernel<3><<<128, 256, 0, stream>>>();
    final_kernel<<<1, 256, 0, stream>>>((float*)d_out);
}

// Round 10
// 99.608 us; speedup vs baseline: 2.5379x; 1.4441x over previous
//
#include <hip/hip_runtime.h>
#include <math.h>

#define NB 2
#define NC 128
#define NN 4096
#define C2L 2.88539008177792681472f   // 2*log2(e)

typedef __attribute__((ext_vector_type(8))) short short8;
typedef __attribute__((ext_vector_type(4))) float f32x4;

// g_Tb: bf16 [n][k], UNSWIZZLED (direct register fragment loads).
// g_Sb: bf16 [n][k], 16B-chunk c stored at c^(n&7) (LDS-bank swizzle baked in;
//       global_load_lds stages it linearly, ds_read applies the XOR).
__device__ unsigned short g_Tb[NB][NN][NC];
__device__ unsigned short g_Sb[NB][NN][NC];
__device__ float g_tsqr[NB][NN];
__device__ float g_ssqr[NB][NN];
__device__ float g_rowS[NB][NN];    // -(2*log2e/(rowmin+eps))
__device__ float g_rowLZ[NB][NN];   // log2(ZB)
__device__ float g_rowE[NB][NN];    // mA
__device__ float g_colS[NB][NN];
__device__ float g_colLZ[NB][NN];
__device__ float g_colE[NB][NN];
__device__ float g_colpart[NB][128][NN];  // slot = stripe*4 + wave, exclusive
__device__ float g_rowpart[NB][16][NN];   // slot = panel, exclusive

#if __has_builtin(__builtin_amdgcn_exp2f)
__device__ __forceinline__ float fexp2(float x) { return __builtin_amdgcn_exp2f(x); }
#else
__device__ __forceinline__ float fexp2(float x) { return exp2f(x); }
#endif

#define GLL16(gsrc, ldst) \
  __builtin_amdgcn_global_load_lds((const __attribute__((address_space(1))) void*)(gsrc), \
                                   (__attribute__((address_space(3))) void*)(ldst), 16, 0, 0)

__device__ __forceinline__ unsigned f2bf(float f) {
    unsigned u = __float_as_uint(f);
    u += 0x7FFFu + ((u >> 16) & 1u);   // RNE
    return u >> 16;
}

// fp32 [k][n] -> bf16 [n][k]; S gets the chunk-XOR swizzle, T stays linear.
__global__ void __launch_bounds__(256) transpose_prep(const float* __restrict__ src,
                                                      const float* __restrict__ tgt) {
    __shared__ float ls[NC][68];
    int bid = blockIdx.x;              // 2 mat x 2 b x 64 n-chunks = 256
    int mat = bid >> 7;                // 0 = S (src), 1 = T (tgt)
    int b   = (bid >> 6) & 1;
    int n0  = (bid & 63) << 6;
    int tid = threadIdx.x;
    const float* in = (mat ? tgt : src) + (size_t)b * NC * NN;
    unsigned short (*out)[NC] = mat ? g_Tb[b] : g_Sb[b];
    float* sq = mat ? g_tsqr[b] : g_ssqr[b];

    for (int idx = tid; idx < NC * 16; idx += 256) {
        int k = idx >> 4, c4 = (idx & 15) << 2;
        *(float4*)&ls[k][c4] = *(const float4*)(in + (size_t)k * NN + n0 + c4);
    }
    __syncthreads();
    {
        int n = tid & 63, c = tid >> 6;
        for (int cc = c; cc < 16; cc += 4) {
            unsigned uo[4];
            #pragma unroll
            for (int e = 0; e < 4; ++e) {
                unsigned lo = f2bf(ls[cc * 8 + 2 * e][n]);
                unsigned hi = f2bf(ls[cc * 8 + 2 * e + 1][n]);
                uo[e] = lo | (hi << 16);
            }
            int swz = mat ? cc : (cc ^ (n & 7));
            *(uint4*)&out[n0 + n][swz * 8] = make_uint4(uo[0], uo[1], uo[2], uo[3]);
        }
    }
    if (tid < 64) {
        float s = 0.f;
        #pragma unroll 8
        for (int k = 0; k < NC; ++k) { float v = ls[k][tid]; s = fmaf(v, v, s); }
        sq[n0 + tid] = s;
    }
}

// One-shot-staged sweep: block = 128 T-rows (wave owns 32) x 256 S-cols.
// S-panel (64KB) staged ONCE via global_load_lds; A-frags + row aux in regs
// (issued before the single barrier). Main loop: pure LDS ds_read + MFMA +
// epilogue, ZERO global loads except the prefetched per-tile col aux.
template<int PASS>
__global__ void __launch_bounds__(256) sweep_kernel() {
    __shared__ unsigned short Sp[256 * NC];   // 64KB, swizzled image

    int bid = blockIdx.x;              // NB*32*16 = 1024
    int b   = bid >> 9;
    int st  = (bid >> 4) & 31;
    int pn  = bid & 15;
    int i0  = st * 128;
    int j0  = pn * 256;
    int tid = threadIdx.x;
    int w = tid >> 6, lane = tid & 63, q = lane >> 4, x = lane & 15;
    int iw = i0 + w * 32;

    // A-fragments (global, unswizzled) -- issued first, overlap the stage
    short8 af[2][4];
    #pragma unroll
    for (int m = 0; m < 2; ++m)
        #pragma unroll
        for (int kk = 0; kk < 4; ++kk)
            af[m][kk] = *(const short8*)&g_Tb[b][iw + m * 16 + x][(kk * 4 + q) * 8];

    // per-row aux (rows iw + m*16 + q*4 + v)
    float tq[8], rS[8], rC[8];
    #pragma unroll
    for (int m = 0; m < 2; ++m)
        #pragma unroll
        for (int v = 0; v < 4; ++v) {
            int row = iw + m * 16 + q * 4 + v;
            tq[m * 4 + v] = g_tsqr[b][row];
            rS[m * 4 + v] = (PASS >= 2) ? g_rowS[b][row] : 0.f;
            rC[m * 4 + v] = (PASS == 3) ? (C2L - g_rowLZ[b][row]) : 0.f;
        }

    // stage the 256-row S-panel: 4096 lane-chunks, linear LDS dest
    #pragma unroll
    for (int it = 0; it < 16; ++it) {
        int l = tid + it * 256;
        GLL16(&g_Sb[b][j0 + (l >> 4)][(l & 15) * 8], &Sp[l * 8]);
    }

    // col aux for tile 0 (prefetch-1 pipeline)
    float sqc[4], cSc[4], cCc[4], sqn[4], cSn[4], cCn[4];
    #pragma unroll
    for (int n = 0; n < 4; ++n) {
        int col = j0 + n * 16 + x;
        sqn[n] = g_ssqr[b][col];
        cSn[n] = (PASS >= 2) ? g_colS[b][col] : 0.f;
        cCn[n] = (PASS == 3) ? (C2L - g_colLZ[b][col]) : 0.f;
    }

    float rstate[8];
    #pragma unroll
    for (int e = 0; e < 8; ++e)
        rstate[e] = (PASS == 1) ? 3.0e38f : (PASS == 2 ? 0.f : -3.0e38f);

    __syncthreads();   // single drain: stage + af + aux all landed

    for (int jt = 0; jt < 4; ++jt) {
        #pragma unroll
        for (int n = 0; n < 4; ++n) { sqc[n] = sqn[n]; cSc[n] = cSn[n]; cCc[n] = cCn[n]; }
        if (jt < 3) {
            #pragma unroll
            for (int n = 0; n < 4; ++n) {
                int col = j0 + (jt + 1) * 64 + n * 16 + x;
                sqn[n] = g_ssqr[b][col];
                if (PASS >= 2) cSn[n] = g_colS[b][col];
                if (PASS == 3) cCn[n] = C2L - g_colLZ[b][col];
            }
        }

        f32x4 acc[2][4];
        #pragma unroll
        for (int m = 0; m < 2; ++m)
            #pragma unroll
            for (int n = 0; n < 4; ++n)
                acc[m][n] = (f32x4){0.f, 0.f, 0.f, 0.f};

        #pragma unroll
        for (int kk = 0; kk < 4; ++kk) {
            short8 bf[4];
            #pragma unroll
            for (int n = 0; n < 4; ++n) {
                int r  = jt * 64 + n * 16 + x;
                int ch = (kk * 4 + q) ^ (r & 7);
                bf[n] = *(const short8*)&Sp[r * NC + ch * 8];
            }
            #pragma unroll
            for (int m = 0; m < 2; ++m)
                #pragma unroll
                for (int n = 0; n < 4; ++n)
                    acc[m][n] = __builtin_amdgcn_mfma_f32_16x16x32_bf16(af[m][kk], bf[n], acc[m][n], 0, 0, 0);
        }

        float cstate[4];
        #pragma unroll
        for (int n = 0; n < 4; ++n)
            cstate[n] = (PASS == 1) ? 3.0e38f : (PASS == 2 ? 0.f : -3.0e38f);

        #pragma unroll
        for (int m = 0; m < 2; ++m)
            #pragma unroll
            for (int n = 0; n < 4; ++n)
                #pragma unroll
                for (int v = 0; v < 4; ++v) {
                    float dv = fmaxf(fmaf(-2.f, acc[m][n][v], tq[m * 4 + v] + sqc[n]), 0.f);
                    if (PASS == 1) {
                        rstate[m * 4 + v] = fminf(rstate[m * 4 + v], dv);
                        cstate[n]         = fminf(cstate[n], dv);
                    } else if (PASS == 2) {
                        rstate[m * 4 + v] += fexp2(fmaf(dv, rS[m * 4 + v], C2L));
                        cstate[n]         += fexp2(fmaf(dv, cSc[n], C2L));
                    } else {
                        rstate[m * 4 + v] = fmaxf(rstate[m * 4 + v], fmaf(dv, cSc[n], cCc[n]));
                        cstate[n]         = fmaxf(cstate[n], fmaf(dv, rS[m * 4 + v], rC[m * 4 + v]));
                    }
                }

        // col partial: reduce over q-groups (rows within wave), exclusive store
        #pragma unroll
        for (int off = 16; off < 64; off <<= 1)
            #pragma unroll
            for (int n = 0; n < 4; ++n) {
                float o = __shfl_xor(cstate[n], off);
                cstate[n] = (PASS == 1) ? fminf(cstate[n], o)
                           : (PASS == 2) ? cstate[n] + o : fmaxf(cstate[n], o);
            }
        if (q == 0)
            #pragma unroll
            for (int n = 0; n < 4; ++n)
                g_colpart[b][st * 4 + w][j0 + jt * 64 + n * 16 + x] = cstate[n];
    }

    // row partial: reduce over 16 x-lanes, exclusive store (wave owns rows)
    #pragma unroll
    for (int off = 1; off < 16; off <<= 1)
        #pragma unroll
        for (int e = 0; e < 8; ++e) {
            float o = __shfl_xor(rstate[e], off);
            rstate[e] = (PASS == 1) ? fminf(rstate[e], o)
                       : (PASS == 2) ? rstate[e] + o : fmaxf(rstate[e], o);
        }
    if (x == 0)
        #pragma unroll
        for (int e = 0; e < 8; ++e)
            g_rowpart[b][pn][iw + (e >> 2) * 16 + q * 4 + (e & 3)] = rstate[e];
}

// Reduce: col over 128 slots, row over 16 slots; 4-lane split per element.
template<int PASS>
__global__ void __launch_bounds__(256) reduce_kernel() {
    int bid = blockIdx.x;             // NB*64 = 128
    int b = bid >> 6, g = bid & 63;
    int tid = threadIdx.x;
    int el = g * 64 + (tid >> 2);
    int part = tid & 3;

    float ca = (PASS == 1) ? 3.0e38f : (PASS == 2 ? 0.f : -3.0e38f);
    float ra = ca;
    #pragma unroll 4
    for (int s = part * 32; s < part * 32 + 32; ++s) {
        float cv = g_colpart[b][s][el];
        if (PASS == 1) ca = fminf(ca, cv);
        else if (PASS == 2) ca += cv;
        else ca = fmaxf(ca, cv);
    }
    #pragma unroll
    for (int s = part * 4; s < part * 4 + 4; ++s) {
        float rv = g_rowpart[b][s][el];
        if (PASS == 1) ra = fminf(ra, rv);
        else if (PASS == 2) ra += rv;
        else ra = fmaxf(ra, rv);
    }
    #pragma unroll
    for (int off = 1; off < 4; off <<= 1) {
        float co = __shfl_xor(ca, off), ro = __shfl_xor(ra, off);
        if (PASS == 1) { ca = fminf(ca, co); ra = fminf(ra, ro); }
        else if (PASS == 2) { ca += co; ra += ro; }
        else { ca = fmaxf(ca, co); ra = fmaxf(ra, ro); }
    }
    if (part == 0) {
        if (PASS == 1) { g_colS[b][el] = -(C2L / (ca + 1e-5f)); g_rowS[b][el] = -(C2L / (ra + 1e-5f)); }
        if (PASS == 2) { g_colLZ[b][el] = log2f(ca);            g_rowLZ[b][el] = log2f(ra); }
        if (PASS == 3) { g_colE[b][el] = fexp2(ca);             g_rowE[b][el] = fexp2(ra); }
    }
}

__global__ void final_kernel(float* __restrict__ out) {
    int tid = threadIdx.x;
    float s[4] = {0.f, 0.f, 0.f, 0.f};
    for (int i = tid; i < NN; i += 256) {
        s[0] += g_rowE[0][i];
        s[1] += g_rowE[1][i];
        s[2] += g_colE[0][i];
        s[3] += g_colE[1][i];
    }
    __shared__ float red[4][4];
    int lane = tid & 63, w = tid >> 6;
    #pragma unroll
    for (int t = 0; t < 4; ++t) {
        float v = s[t];
        #pragma unroll
        for (int off = 32; off; off >>= 1) v += __shfl_down(v, off);
        if (lane == 0) red[t][w] = v;
    }
    __syncthreads();
    if (tid == 0) {
        float o = 0.f;
        #pragma unroll
        for (int t = 0; t < 4; ++t) {
            float S = red[t][0] + red[t][1] + red[t][2] + red[t][3];
            o += logf(S);
        }
        out[0] = logf((float)NN) - 0.25f * o;
    }
}

extern "C" void kernel_launch(void* const* d_in, const int* in_sizes, int n_in,
                              void* d_out, int out_size, void* d_ws, size_t ws_size,
                              hipStream_t stream) {
    const float* src = (const float*)d_in[0];
    const float* tgt = (const float*)d_in[1];
    (void)in_sizes; (void)n_in; (void)d_ws; (void)ws_size; (void)out_size;

    transpose_prep<<<256, 256, 0, stream>>>(src, tgt);
    sweep_kernel<1><<<1024, 256, 0, stream>>>();
    reduce_kernel<1><<<128, 256, 0, stream>>>();
    sweep_kernel<2><<<1024, 256, 0, stream>>>();
    reduce_kernel<2><<<128, 256, 0, stream>>>();
    sweep_kernel<3><<<1024, 256, 0, stream>>>();
    reduce_kernel<3><<<128, 256, 0, stream>>>();
    final_kernel<<<1, 256, 0, stream>>>((float*)d_out);
}